// Round 20
// baseline (250.189 us; speedup 1.0000x reference)
//
#include <hip/hip_runtime.h>

// GCN 4-layer forward on MI355X.
// Reference: h' = relu( norm_dst * segsum_{dst}( ((h*norm_src) @ W)[src] ) + b )
//
// Round 20:
//  - UNFUSED drain: r19 showed deg+gemm0 co-residency stretches the atomic
//    drain 62->79us (fabric interference). deg_loc standalone (r16, 62us);
//    gemm0 standalone LDS-free MFMA (~5us).
//  - gather4: each 16-lane group (8 for D=64) owns ONE node, 4-deep
//    predicated edge walk -> 16 rows in flight/wave (2x r18), and NO
//    cross-lane reduce (group writes its own row).

namespace {

constexpr int NN = 50000;      // nodes
constexpr int NE = 600000;     // edges
constexpr int SCAN_BLK = 256;
constexpr int NBLK = (NN + SCAN_BLK - 1) / SCAN_BLK;  // 196
constexpr int EB = (NE + 255) / 256;                  // 2344 edge blocks
constexpr int MFMA_BLOCKS = (NN / 16 + 3) / 4;        // 782
constexpr int WCVT_ELEMS = 16384 * 3 + 8192;          // W0,W1,W2 + W3
constexpr int WCVT_BLOCKS = WCVT_ELEMS / 256;         // 224

typedef unsigned short bhalf;
typedef __attribute__((ext_vector_type(8))) short short8v;   // 8 bf16
typedef __attribute__((ext_vector_type(4))) float f32x4;

__device__ inline float blo(unsigned int v) {  // low bf16 of a packed word
  return __uint_as_float(v << 16);
}
__device__ inline float bhi(unsigned int v) {  // high bf16 of a packed word
  return __uint_as_float(v & 0xFFFF0000u);
}
__device__ inline unsigned int f2b_bits(float f) {  // RNE bf16 in high 16 bits
  unsigned int b = __float_as_uint(f);
  return b + 0x7FFFu + ((b >> 16) & 1u);
}
__device__ inline unsigned int pack2(float lo, float hi) {
  return (f2b_bits(lo) >> 16) | (f2b_bits(hi) & 0xFFFF0000u);
}
__device__ inline bhalf f2b(float f) { return (bhalf)(f2b_bits(f) >> 16); }

// ---- upfront: Wt[j][k] = bf16(W[k][j]) for all four layer weights ----
__global__ __launch_bounds__(256) void wcvt_kernel(
    const float* __restrict__ W0, const float* __restrict__ W1,
    const float* __restrict__ W2, const float* __restrict__ W3,
    bhalf* __restrict__ wt0, bhalf* __restrict__ wt1,
    bhalf* __restrict__ wt2, bhalf* __restrict__ wt3) {
  int flat = blockIdx.x * 256 + threadIdx.x;
  if (flat < 16384) {
    int j = flat >> 7, k = flat & 127;
    wt0[flat] = f2b(W0[k * 128 + j]);
  } else if (flat < 32768) {
    int f = flat - 16384;
    int j = f >> 7, k = f & 127;
    wt1[f] = f2b(W1[k * 128 + j]);
  } else if (flat < 49152) {
    int f = flat - 32768;
    int j = f >> 7, k = f & 127;
    wt2[f] = f2b(W2[k * 128 + j]);
  } else {
    int f = flat - 49152;
    int j = f >> 7, k = f & 127;
    wt3[f] = f2b(W3[k * 64 + j]);
  }
}

// degree counting + le slots, full-grid single-edge-per-thread (62us floor)
__global__ void deg_loc_kernel(const int* __restrict__ src, const int* __restrict__ dst,
                               int* __restrict__ dego, int* __restrict__ degi,
                               int* __restrict__ le) {
  int e = blockIdx.x * blockDim.x + threadIdx.x;
  if (e < NE) {
    atomicAdd(&dego[src[e]], 1);
    le[e] = atomicAdd(&degi[dst[e]], 1);
  }
}

// --- scan phase 1 + norms ---
__global__ __launch_bounds__(SCAN_BLK) void scan1_norm(const int* __restrict__ dego,
                                                       const int* __restrict__ degi,
                                                       int* __restrict__ bsum,
                                                       float* __restrict__ ns,
                                                       float* __restrict__ nd) {
  __shared__ int ws[SCAN_BLK / 64];
  int i = blockIdx.x * SCAN_BLK + threadIdx.x;
  int v = 0;
  if (i < NN) {
    int din = degi[i];
    int dout = dego[i];
    v = din;
    int a = dout < 1 ? 1 : dout;
    int b = din < 1 ? 1 : din;
    ns[i] = 1.0f / sqrtf((float)a);
    nd[i] = 1.0f / sqrtf((float)b);
  }
#pragma unroll
  for (int off = 32; off; off >>= 1) v += __shfl_down(v, off, 64);
  int lane = threadIdx.x & 63, w = threadIdx.x >> 6;
  if (lane == 0) ws[w] = v;
  __syncthreads();
  if (threadIdx.x == 0) {
    int s = 0;
#pragma unroll
    for (int k = 0; k < SCAN_BLK / 64; ++k) s += ws[k];
    bsum[blockIdx.x] = s;
  }
}

// --- scan phases 2+3 merged: each block re-derives its prefix from bsum ---
__global__ __launch_bounds__(SCAN_BLK) void scan23(const int* __restrict__ deg,
                                                   const int* __restrict__ bsum,
                                                   int* __restrict__ rowptr) {
  __shared__ int sb[SCAN_BLK];   // bsum inclusive scan
  __shared__ int s[SCAN_BLK];    // local deg scan
  const int t = threadIdx.x;
  int vb = (t < NBLK) ? bsum[t] : 0;
  sb[t] = vb;
  __syncthreads();
  for (int off = 1; off < SCAN_BLK; off <<= 1) {
    int u = (t >= off) ? sb[t - off] : 0;
    __syncthreads();
    sb[t] += u;
    __syncthreads();
  }
  const int pre = (blockIdx.x == 0) ? 0 : sb[blockIdx.x - 1];
  if (blockIdx.x == NBLK - 1 && t == 0) rowptr[NN] = sb[NBLK - 1];  // == NE

  int i = blockIdx.x * SCAN_BLK + t;
  int v = (i < NN) ? deg[i] : 0;
  s[t] = v;
  __syncthreads();
  for (int off = 1; off < SCAN_BLK; off <<= 1) {
    int u = (t >= off) ? s[t - off] : 0;
    __syncthreads();
    s[t] += u;
    __syncthreads();
  }
  if (i < NN) rowptr[i] = pre + s[t] - v;
}

// atomic-free CSR fill using le slots recorded during counting
__global__ void scatter_kernel(const int* __restrict__ src, const int* __restrict__ dst,
                               const int* __restrict__ le, const int* __restrict__ rowptr,
                               int* __restrict__ col) {
  int e = blockIdx.x * blockDim.x + threadIdx.x;
  if (e < NE) col[rowptr[dst[e]] + le[e]] = src[e];
}

// ---- bf16 MFMA GEMM: one wave per 16-row tile; LDS-free ----
// TH=float: h is fp32, converted to bf16 A-frags in-reg (layer 0).
// USE_NS: multiply rows by ns in the epilogue.
template <int DO, bool USE_NS, typename TH>
__global__ __launch_bounds__(256, 2) void gemm_mfma(const TH* __restrict__ h,
                                                    const bhalf* __restrict__ wt,
                                                    const float* __restrict__ ns,
                                                    bhalf* __restrict__ x) {
  constexpr int CF = DO / 16;  // col fragments: 8 or 4
  const int lane = threadIdx.x & 63;
  const int wv = threadIdx.x >> 6;
  const int tile = blockIdx.x * 4 + wv;
  if (tile >= NN / 16) return;
  const int row0 = tile * 16;
  const size_t arow = (size_t)(row0 + (lane & 15)) * 128;
  const int koff = (lane >> 4) * 8;
  const int bcol = lane & 15;

  f32x4 acc[CF];
#pragma unroll
  for (int cf = 0; cf < CF; ++cf) acc[cf] = (f32x4){0.f, 0.f, 0.f, 0.f};

#pragma unroll
  for (int ks = 0; ks < 4; ++ks) {
    const int k0 = ks * 32 + koff;
    short8v av;
    if constexpr (sizeof(TH) == 4) {
      float4 ha = *reinterpret_cast<const float4*>(&h[arow + k0]);
      float4 hb = *reinterpret_cast<const float4*>(&h[arow + k0 + 4]);
      av[0] = (short)f2b(ha.x); av[1] = (short)f2b(ha.y);
      av[2] = (short)f2b(ha.z); av[3] = (short)f2b(ha.w);
      av[4] = (short)f2b(hb.x); av[5] = (short)f2b(hb.y);
      av[6] = (short)f2b(hb.z); av[7] = (short)f2b(hb.w);
    } else {
      av = *reinterpret_cast<const short8v*>(&h[arow + k0]);
    }
#pragma unroll
    for (int cf = 0; cf < CF; ++cf) {
      short8v bv = *reinterpret_cast<const short8v*>(
          &wt[(size_t)(cf * 16 + bcol) * 128 + k0]);
      acc[cf] = __builtin_amdgcn_mfma_f32_16x16x32_bf16(av, bv, acc[cf], 0, 0, 0);
    }
  }

  const int crow = row0 + ((lane >> 4) << 2);
  float nsv[4] = {1.f, 1.f, 1.f, 1.f};
  if constexpr (USE_NS) {
#pragma unroll
    for (int r = 0; r < 4; ++r) nsv[r] = ns[crow + r];
  }
#pragma unroll
  for (int cf = 0; cf < CF; ++cf) {
#pragma unroll
    for (int r = 0; r < 4; ++r) {
      x[(size_t)(crow + r) * DO + cf * 16 + bcol] = f2b(acc[cf][r] * nsv[r]);
    }
  }
}

// ---- gather4: each LPR-lane group owns ONE node ----
// LPR = D/8 lanes cover a row (8 bf16/lane via uint4); NPW = 64/LPR nodes
// per wave (4 or 8; divides NN). Per group-iteration: 4-deep predicated
// edge walk -> 4 independent row fetches per group, 16/wave. No cross-lane
// reduce: the group writes its node's row directly with nd/bias(/relu).
// OUTBF: bf16 out vs fp32 (final). NSRC (layer 0): ns[col] per edge.
template <int D, bool RELU, bool NSRC, bool OUTBF>
__global__ __launch_bounds__(256) void gather4_kernel(const bhalf* __restrict__ x,
                                                      const int* __restrict__ rowptr,
                                                      const int* __restrict__ col,
                                                      const float* __restrict__ nd,
                                                      const float* __restrict__ b,
                                                      const float* __restrict__ nsv,
                                                      void* __restrict__ outp) {
  constexpr int LPR = D / 8;     // 16 (D=128) or 8 (D=64)
  constexpr int NPW = 64 / LPR;  // 4 or 8 nodes per wave
  const int wid = (blockIdx.x * blockDim.x + threadIdx.x) >> 6;
  if (wid * NPW >= NN) return;   // NN % NPW == 0: all resident groups valid
  const int lane = threadIdx.x & 63;
  const int g = lane / LPR;
  const int ci = (lane % LPR) * 8;
  const int n = wid * NPW + g;
  const int beg = rowptr[n];
  const int end = rowptr[n + 1];

  float a[8];
#pragma unroll
  for (int k = 0; k < 8; ++k) a[k] = 0.f;

  for (int e = beg; e < end; e += 4) {  // per-group walk, 4-deep
    const bool p1 = e + 1 < end;
    const bool p2 = e + 2 < end;
    const bool p3 = e + 3 < end;
    const int c0 = col[e];
    const int c1 = col[p1 ? e + 1 : e];
    const int c2 = col[p2 ? e + 2 : e];
    const int c3 = col[p3 ? e + 3 : e];
    const float s0 = NSRC ? nsv[c0] : 1.0f;
    const float s1 = p1 ? (NSRC ? nsv[c1] : 1.0f) : 0.0f;
    const float s2 = p2 ? (NSRC ? nsv[c2] : 1.0f) : 0.0f;
    const float s3 = p3 ? (NSRC ? nsv[c3] : 1.0f) : 0.0f;
    const uint4 v0 = *reinterpret_cast<const uint4*>(&x[(size_t)c0 * D + ci]);
    const uint4 v1 = *reinterpret_cast<const uint4*>(&x[(size_t)c1 * D + ci]);
    const uint4 v2 = *reinterpret_cast<const uint4*>(&x[(size_t)c2 * D + ci]);
    const uint4 v3 = *reinterpret_cast<const uint4*>(&x[(size_t)c3 * D + ci]);
    float f0[8], f1[8], f2[8], f3[8];
    f0[0] = blo(v0.x); f0[1] = bhi(v0.x); f0[2] = blo(v0.y); f0[3] = bhi(v0.y);
    f0[4] = blo(v0.z); f0[5] = bhi(v0.z); f0[6] = blo(v0.w); f0[7] = bhi(v0.w);
    f1[0] = blo(v1.x); f1[1] = bhi(v1.x); f1[2] = blo(v1.y); f1[3] = bhi(v1.y);
    f1[4] = blo(v1.z); f1[5] = bhi(v1.z); f1[6] = blo(v1.w); f1[7] = bhi(v1.w);
    f2[0] = blo(v2.x); f2[1] = bhi(v2.x); f2[2] = blo(v2.y); f2[3] = bhi(v2.y);
    f2[4] = blo(v2.z); f2[5] = bhi(v2.z); f2[6] = blo(v2.w); f2[7] = bhi(v2.w);
    f3[0] = blo(v3.x); f3[1] = bhi(v3.x); f3[2] = blo(v3.y); f3[3] = bhi(v3.y);
    f3[4] = blo(v3.z); f3[5] = bhi(v3.z); f3[6] = blo(v3.w); f3[7] = bhi(v3.w);
#pragma unroll
    for (int k = 0; k < 8; ++k) {
      a[k] = fmaf(s0, f0[k], fmaf(s1, f1[k], fmaf(s2, f2[k], fmaf(s3, f3[k], a[k]))));
    }
  }

  const float s = nd[n];
  float4 b0 = *reinterpret_cast<const float4*>(&b[ci]);
  float4 b1 = *reinterpret_cast<const float4*>(&b[ci + 4]);
  float r[8];
  r[0] = fmaf(a[0], s, b0.x); r[1] = fmaf(a[1], s, b0.y);
  r[2] = fmaf(a[2], s, b0.z); r[3] = fmaf(a[3], s, b0.w);
  r[4] = fmaf(a[4], s, b1.x); r[5] = fmaf(a[5], s, b1.y);
  r[6] = fmaf(a[6], s, b1.z); r[7] = fmaf(a[7], s, b1.w);
  if (RELU) {
#pragma unroll
    for (int k = 0; k < 8; ++k) r[k] = fmaxf(r[k], 0.f);
  }
  if constexpr (OUTBF) {
    bhalf* out = (bhalf*)outp;
    uint4 p;
    p.x = pack2(r[0], r[1]);
    p.y = pack2(r[2], r[3]);
    p.z = pack2(r[4], r[5]);
    p.w = pack2(r[6], r[7]);
    *reinterpret_cast<uint4*>(&out[(size_t)n * D + ci]) = p;
  } else {
    float* out = (float*)outp;
    *reinterpret_cast<float4*>(&out[(size_t)n * D + ci]) =
        make_float4(r[0], r[1], r[2], r[3]);
    *reinterpret_cast<float4*>(&out[(size_t)n * D + ci + 4]) =
        make_float4(r[4], r[5], r[6], r[7]);
  }
}

}  // namespace

extern "C" void kernel_launch(void* const* d_in, const int* in_sizes, int n_in,
                              void* d_out, int out_size, void* d_ws, size_t ws_size,
                              hipStream_t stream) {
  const float* h0  = (const float*)d_in[0];
  const int*   src = (const int*)d_in[1];
  const int*   dst = (const int*)d_in[2];
  const float* W0 = (const float*)d_in[3];
  const float* b0 = (const float*)d_in[4];
  const float* W1 = (const float*)d_in[5];
  const float* b1 = (const float*)d_in[6];
  const float* W2 = (const float*)d_in[7];
  const float* b2 = (const float*)d_in[8];
  const float* W3 = (const float*)d_in[9];
  const float* b3 = (const float*)d_in[10];
  float* out = (float*)d_out;

  // workspace layout (256B aligned)
  char* w = (char*)d_ws;
  size_t off = 0;
  auto take = [&](size_t bytes) {
    char* p = w + off;
    off = (off + bytes + 255) & ~size_t(255);
    return p;
  };
  int*   deg_out = (int*)take(NN * 4);   // adjacent: one memset covers both
  int*   deg_in  = (int*)take(NN * 4);
  float* nsrc    = (float*)take(NN * 4);
  float* ndst    = (float*)take(NN * 4);
  int*   rowptr  = (int*)take((NN + 1) * 4);
  int*   le      = (int*)take(NE * 4);
  int*   col     = (int*)take(NE * 4);
  int*   bsum    = (int*)take(NBLK * 4);
  bhalf* xbuf    = (bhalf*)take((size_t)NN * 128 * 2);  // bf16 GEMM outputs
  bhalf* hbuf    = (bhalf*)take((size_t)NN * 128 * 2);  // bf16 gather outputs
  bhalf* wt0     = (bhalf*)take(128 * 128 * 2);         // W0^T bf16
  bhalf* wt1     = (bhalf*)take(128 * 128 * 2);         // W1^T bf16
  bhalf* wt2     = (bhalf*)take(128 * 128 * 2);         // W2^T bf16
  bhalf* wt3     = (bhalf*)take(64 * 128 * 2);          // W3^T bf16
  (void)ws_size; (void)in_sizes; (void)n_in; (void)out_size;

  // zero both degree arrays (contiguous)
  hipMemsetAsync(deg_out, 0, (size_t)((char*)nsrc - (char*)deg_out), stream);

  // 0) W -> Wt bf16 (all four), tiny
  wcvt_kernel<<<WCVT_BLOCKS, 256, 0, stream>>>(W0, W1, W2, W3, wt0, wt1, wt2, wt3);
  // 1) layer-0 GEMM standalone (LDS-free MFMA, ~5us): x0 = bf16(h0) @ wt0
  gemm_mfma<128, false, float><<<MFMA_BLOCKS, 256, 0, stream>>>(h0, wt0, nullptr, xbuf);
  // 2) degree atomics standalone at full issue rate (62us floor)
  deg_loc_kernel<<<EB, 256, 0, stream>>>(src, dst, deg_out, deg_in, le);
  // 3) scan chain
  scan1_norm<<<NBLK, SCAN_BLK, 0, stream>>>(deg_out, deg_in, bsum, nsrc, ndst);
  scan23<<<NBLK, SCAN_BLK, 0, stream>>>(deg_in, bsum, rowptr);
  // 4) CSR fill
  scatter_kernel<<<EB, 256, 0, stream>>>(src, dst, le, rowptr, col);

  const int G4_128 = (NN / 4 * 64) / 256;        // 3125
  const int G4_64  = (NN / 8 * 64 + 255) / 256;  // 1563

  // layer 0: x0 unscaled bf16 -> gather applies ns[col]; h1 bf16
  gather4_kernel<128, true, true, true><<<G4_128, 256, 0, stream>>>(
      xbuf, rowptr, col, ndst, b0, nsrc, hbuf);
  // layer 1 (MFMA)
  gemm_mfma<128, true, bhalf><<<MFMA_BLOCKS, 256, 0, stream>>>(hbuf, wt1, nsrc, xbuf);
  gather4_kernel<128, true, false, true><<<G4_128, 256, 0, stream>>>(
      xbuf, rowptr, col, ndst, b1, nullptr, hbuf);
  // layer 2 (MFMA)
  gemm_mfma<128, true, bhalf><<<MFMA_BLOCKS, 256, 0, stream>>>(hbuf, wt2, nsrc, xbuf);
  gather4_kernel<128, true, false, true><<<G4_128, 256, 0, stream>>>(
      xbuf, rowptr, col, ndst, b2, nullptr, hbuf);
  // layer 3 (MFMA, DO=64): no relu, fp32 straight to d_out
  gemm_mfma<64, true, bhalf><<<MFMA_BLOCKS, 256, 0, stream>>>(hbuf, wt3, nsrc, xbuf);
  gather4_kernel<64, false, false, false><<<G4_64, 256, 0, stream>>>(
      xbuf, rowptr, col, ndst, b3, nullptr, out);
}

// Round 21
// 248.013 us; speedup vs baseline: 1.0088x; 1.0088x over previous
//
#include <hip/hip_runtime.h>

// GCN 4-layer forward on MI355X.
// Reference: h' = relu( norm_dst * segsum_{dst}( ((h*norm_src) @ W)[src] ) + b )
//
// Round 21: consolidation. Component floors (measured over r8-r20): atomic
// drain ~60us (memory-side 32B-sector RMWs), gathers ~25us each (L2/L3
// random-row service), scatter ~25-30us. Remaining slack = dispatch count.
//  - wcvt (240KB reads) rides in deg_loc's grid (negligible interference,
//    unlike r19's 38MB gemm0 which stretched the drain 62->79).
//  - gemm0 (LDS-free MFMA) rides in scan1_norm's grid (196-block scan leaves
//    the machine idle; 782 gemm blocks fill it).
//  13 -> 11 dispatches.

namespace {

constexpr int NN = 50000;      // nodes
constexpr int NE = 600000;     // edges
constexpr int SCAN_BLK = 256;
constexpr int NBLK = (NN + SCAN_BLK - 1) / SCAN_BLK;  // 196
constexpr int EB = (NE + 255) / 256;                  // 2344 edge blocks
constexpr int MFMA_BLOCKS = (NN / 16 + 3) / 4;        // 782
constexpr int WCVT_ELEMS = 16384 * 3 + 8192;          // W0,W1,W2 + W3
constexpr int WCVT_BLOCKS = WCVT_ELEMS / 256;         // 224

typedef unsigned short bhalf;
typedef __attribute__((ext_vector_type(8))) short short8v;   // 8 bf16
typedef __attribute__((ext_vector_type(4))) float f32x4;

__device__ inline float blo(unsigned int v) {  // low bf16 of a packed word
  return __uint_as_float(v << 16);
}
__device__ inline float bhi(unsigned int v) {  // high bf16 of a packed word
  return __uint_as_float(v & 0xFFFF0000u);
}
__device__ inline unsigned int f2b_bits(float f) {  // RNE bf16 in high 16 bits
  unsigned int b = __float_as_uint(f);
  return b + 0x7FFFu + ((b >> 16) & 1u);
}
__device__ inline unsigned int pack2(float lo, float hi) {
  return (f2b_bits(lo) >> 16) | (f2b_bits(hi) & 0xFFFF0000u);
}
__device__ inline bhalf f2b(float f) { return (bhalf)(f2b_bits(f) >> 16); }

// ---- fused: degree/le atomics (full parallelism) + W->Wt bf16 convert ----
// blocks [0,EB): 1 edge/thread. blocks [EB,EB+WCVT_BLOCKS): Wt[j][k]=W[k][j].
__global__ void deg_wcvt_kernel(const int* __restrict__ src, const int* __restrict__ dst,
                                int* __restrict__ dego, int* __restrict__ degi,
                                int* __restrict__ le,
                                const float* __restrict__ W0, const float* __restrict__ W1,
                                const float* __restrict__ W2, const float* __restrict__ W3,
                                bhalf* __restrict__ wt0, bhalf* __restrict__ wt1,
                                bhalf* __restrict__ wt2, bhalf* __restrict__ wt3) {
  if (blockIdx.x < EB) {
    int e = blockIdx.x * blockDim.x + threadIdx.x;
    if (e < NE) {
      atomicAdd(&dego[src[e]], 1);
      le[e] = atomicAdd(&degi[dst[e]], 1);
    }
    return;
  }
  int flat = (blockIdx.x - EB) * 256 + threadIdx.x;
  if (flat < 16384) {
    int j = flat >> 7, k = flat & 127;
    wt0[flat] = f2b(W0[k * 128 + j]);
  } else if (flat < 32768) {
    int f = flat - 16384;
    int j = f >> 7, k = f & 127;
    wt1[f] = f2b(W1[k * 128 + j]);
  } else if (flat < 49152) {
    int f = flat - 32768;
    int j = f >> 7, k = f & 127;
    wt2[f] = f2b(W2[k * 128 + j]);
  } else {
    int f = flat - 49152;
    int j = f >> 7, k = f & 127;
    wt3[f] = f2b(W3[k * 64 + j]);
  }
}

// ---- MFMA GEMM per-wave body (LDS-free). tile = 16-row tile index. ----
template <int DO, bool USE_NS, typename TH>
__device__ void gemm_mfma_body(const TH* __restrict__ h, const bhalf* __restrict__ wt,
                               const float* __restrict__ ns, bhalf* __restrict__ x,
                               int tile) {
  constexpr int CF = DO / 16;  // col fragments: 8 or 4
  const int lane = threadIdx.x & 63;
  const int row0 = tile * 16;
  const size_t arow = (size_t)(row0 + (lane & 15)) * 128;
  const int koff = (lane >> 4) * 8;
  const int bcol = lane & 15;

  f32x4 acc[CF];
#pragma unroll
  for (int cf = 0; cf < CF; ++cf) acc[cf] = (f32x4){0.f, 0.f, 0.f, 0.f};

#pragma unroll
  for (int ks = 0; ks < 4; ++ks) {
    const int k0 = ks * 32 + koff;
    short8v av;
    if constexpr (sizeof(TH) == 4) {
      float4 ha = *reinterpret_cast<const float4*>(&h[arow + k0]);
      float4 hb = *reinterpret_cast<const float4*>(&h[arow + k0 + 4]);
      av[0] = (short)f2b(ha.x); av[1] = (short)f2b(ha.y);
      av[2] = (short)f2b(ha.z); av[3] = (short)f2b(ha.w);
      av[4] = (short)f2b(hb.x); av[5] = (short)f2b(hb.y);
      av[6] = (short)f2b(hb.z); av[7] = (short)f2b(hb.w);
    } else {
      av = *reinterpret_cast<const short8v*>(&h[arow + k0]);
    }
#pragma unroll
    for (int cf = 0; cf < CF; ++cf) {
      short8v bv = *reinterpret_cast<const short8v*>(
          &wt[(size_t)(cf * 16 + bcol) * 128 + k0]);
      acc[cf] = __builtin_amdgcn_mfma_f32_16x16x32_bf16(av, bv, acc[cf], 0, 0, 0);
    }
  }

  const int crow = row0 + ((lane >> 4) << 2);
  float nsv[4] = {1.f, 1.f, 1.f, 1.f};
  if constexpr (USE_NS) {
#pragma unroll
    for (int r = 0; r < 4; ++r) nsv[r] = ns[crow + r];
  }
#pragma unroll
  for (int cf = 0; cf < CF; ++cf) {
#pragma unroll
    for (int r = 0; r < 4; ++r) {
      x[(size_t)(crow + r) * DO + cf * 16 + bcol] = f2b(acc[cf][r] * nsv[r]);
    }
  }
}

// ---- fused: scan phase1 + norms (blocks [0,NBLK)) + layer-0 MFMA GEMM ----
// gemm0: x0 = bf16(h0) @ wt0, unscaled (ns folded into gather-0).
__global__ __launch_bounds__(256, 2) void scan1_gemm0_kernel(
    const int* __restrict__ dego, const int* __restrict__ degi,
    int* __restrict__ bsum, float* __restrict__ ns, float* __restrict__ nd,
    const float* __restrict__ h0, const bhalf* __restrict__ wt0,
    bhalf* __restrict__ x) {
  if (blockIdx.x >= NBLK) {
    const int tile = (blockIdx.x - NBLK) * 4 + (threadIdx.x >> 6);
    if (tile < NN / 16)
      gemm_mfma_body<128, false, float>(h0, wt0, nullptr, x, tile);
    return;
  }
  __shared__ int ws[SCAN_BLK / 64];
  int i = blockIdx.x * SCAN_BLK + threadIdx.x;
  int v = 0;
  if (i < NN) {
    int din = degi[i];
    int dout = dego[i];
    v = din;
    int a = dout < 1 ? 1 : dout;
    int b = din < 1 ? 1 : din;
    ns[i] = 1.0f / sqrtf((float)a);
    nd[i] = 1.0f / sqrtf((float)b);
  }
#pragma unroll
  for (int off = 32; off; off >>= 1) v += __shfl_down(v, off, 64);
  int lane = threadIdx.x & 63, w = threadIdx.x >> 6;
  if (lane == 0) ws[w] = v;
  __syncthreads();
  if (threadIdx.x == 0) {
    int s = 0;
#pragma unroll
    for (int k = 0; k < SCAN_BLK / 64; ++k) s += ws[k];
    bsum[blockIdx.x] = s;
  }
}

// --- scan phases 2+3 merged: each block re-derives its prefix from bsum ---
__global__ __launch_bounds__(SCAN_BLK) void scan23(const int* __restrict__ deg,
                                                   const int* __restrict__ bsum,
                                                   int* __restrict__ rowptr) {
  __shared__ int sb[SCAN_BLK];   // bsum inclusive scan
  __shared__ int s[SCAN_BLK];    // local deg scan
  const int t = threadIdx.x;
  int vb = (t < NBLK) ? bsum[t] : 0;
  sb[t] = vb;
  __syncthreads();
  for (int off = 1; off < SCAN_BLK; off <<= 1) {
    int u = (t >= off) ? sb[t - off] : 0;
    __syncthreads();
    sb[t] += u;
    __syncthreads();
  }
  const int pre = (blockIdx.x == 0) ? 0 : sb[blockIdx.x - 1];
  if (blockIdx.x == NBLK - 1 && t == 0) rowptr[NN] = sb[NBLK - 1];  // == NE

  int i = blockIdx.x * SCAN_BLK + t;
  int v = (i < NN) ? deg[i] : 0;
  s[t] = v;
  __syncthreads();
  for (int off = 1; off < SCAN_BLK; off <<= 1) {
    int u = (t >= off) ? s[t - off] : 0;
    __syncthreads();
    s[t] += u;
    __syncthreads();
  }
  if (i < NN) rowptr[i] = pre + s[t] - v;
}

// atomic-free CSR fill using le slots recorded during counting
__global__ void scatter_kernel(const int* __restrict__ src, const int* __restrict__ dst,
                               const int* __restrict__ le, const int* __restrict__ rowptr,
                               int* __restrict__ col) {
  int e = blockIdx.x * blockDim.x + threadIdx.x;
  if (e < NE) col[rowptr[dst[e]] + le[e]] = src[e];
}

// standalone MFMA GEMM kernel (layers 1-3)
template <int DO, bool USE_NS, typename TH>
__global__ __launch_bounds__(256, 2) void gemm_mfma(const TH* __restrict__ h,
                                                    const bhalf* __restrict__ wt,
                                                    const float* __restrict__ ns,
                                                    bhalf* __restrict__ x) {
  const int tile = blockIdx.x * 4 + (threadIdx.x >> 6);
  if (tile >= NN / 16) return;
  gemm_mfma_body<DO, USE_NS, TH>(h, wt, ns, x, tile);
}

// ---- gather4: each LPR-lane group owns ONE node (r20, verified) ----
// LPR = D/8 lanes cover a row (8 bf16/lane via uint4); NPW = 64/LPR nodes
// per wave. 4-deep predicated edge walk; no cross-lane reduce.
template <int D, bool RELU, bool NSRC, bool OUTBF>
__global__ __launch_bounds__(256) void gather4_kernel(const bhalf* __restrict__ x,
                                                      const int* __restrict__ rowptr,
                                                      const int* __restrict__ col,
                                                      const float* __restrict__ nd,
                                                      const float* __restrict__ b,
                                                      const float* __restrict__ nsv,
                                                      void* __restrict__ outp) {
  constexpr int LPR = D / 8;     // 16 (D=128) or 8 (D=64)
  constexpr int NPW = 64 / LPR;  // 4 or 8 nodes per wave
  const int wid = (blockIdx.x * blockDim.x + threadIdx.x) >> 6;
  if (wid * NPW >= NN) return;   // NN % NPW == 0
  const int lane = threadIdx.x & 63;
  const int g = lane / LPR;
  const int ci = (lane % LPR) * 8;
  const int n = wid * NPW + g;
  const int beg = rowptr[n];
  const int end = rowptr[n + 1];

  float a[8];
#pragma unroll
  for (int k = 0; k < 8; ++k) a[k] = 0.f;

  for (int e = beg; e < end; e += 4) {  // per-group walk, 4-deep
    const bool p1 = e + 1 < end;
    const bool p2 = e + 2 < end;
    const bool p3 = e + 3 < end;
    const int c0 = col[e];
    const int c1 = col[p1 ? e + 1 : e];
    const int c2 = col[p2 ? e + 2 : e];
    const int c3 = col[p3 ? e + 3 : e];
    const float s0 = NSRC ? nsv[c0] : 1.0f;
    const float s1 = p1 ? (NSRC ? nsv[c1] : 1.0f) : 0.0f;
    const float s2 = p2 ? (NSRC ? nsv[c2] : 1.0f) : 0.0f;
    const float s3 = p3 ? (NSRC ? nsv[c3] : 1.0f) : 0.0f;
    const uint4 v0 = *reinterpret_cast<const uint4*>(&x[(size_t)c0 * D + ci]);
    const uint4 v1 = *reinterpret_cast<const uint4*>(&x[(size_t)c1 * D + ci]);
    const uint4 v2 = *reinterpret_cast<const uint4*>(&x[(size_t)c2 * D + ci]);
    const uint4 v3 = *reinterpret_cast<const uint4*>(&x[(size_t)c3 * D + ci]);
    float f0[8], f1[8], f2[8], f3[8];
    f0[0] = blo(v0.x); f0[1] = bhi(v0.x); f0[2] = blo(v0.y); f0[3] = bhi(v0.y);
    f0[4] = blo(v0.z); f0[5] = bhi(v0.z); f0[6] = blo(v0.w); f0[7] = bhi(v0.w);
    f1[0] = blo(v1.x); f1[1] = bhi(v1.x); f1[2] = blo(v1.y); f1[3] = bhi(v1.y);
    f1[4] = blo(v1.z); f1[5] = bhi(v1.z); f1[6] = blo(v1.w); f1[7] = bhi(v1.w);
    f2[0] = blo(v2.x); f2[1] = bhi(v2.x); f2[2] = blo(v2.y); f2[3] = bhi(v2.y);
    f2[4] = blo(v2.z); f2[5] = bhi(v2.z); f2[6] = blo(v2.w); f2[7] = bhi(v2.w);
    f3[0] = blo(v3.x); f3[1] = bhi(v3.x); f3[2] = blo(v3.y); f3[3] = bhi(v3.y);
    f3[4] = blo(v3.z); f3[5] = bhi(v3.z); f3[6] = blo(v3.w); f3[7] = bhi(v3.w);
#pragma unroll
    for (int k = 0; k < 8; ++k) {
      a[k] = fmaf(s0, f0[k], fmaf(s1, f1[k], fmaf(s2, f2[k], fmaf(s3, f3[k], a[k]))));
    }
  }

  const float s = nd[n];
  float4 b0 = *reinterpret_cast<const float4*>(&b[ci]);
  float4 b1 = *reinterpret_cast<const float4*>(&b[ci + 4]);
  float r[8];
  r[0] = fmaf(a[0], s, b0.x); r[1] = fmaf(a[1], s, b0.y);
  r[2] = fmaf(a[2], s, b0.z); r[3] = fmaf(a[3], s, b0.w);
  r[4] = fmaf(a[4], s, b1.x); r[5] = fmaf(a[5], s, b1.y);
  r[6] = fmaf(a[6], s, b1.z); r[7] = fmaf(a[7], s, b1.w);
  if (RELU) {
#pragma unroll
    for (int k = 0; k < 8; ++k) r[k] = fmaxf(r[k], 0.f);
  }
  if constexpr (OUTBF) {
    bhalf* out = (bhalf*)outp;
    uint4 p;
    p.x = pack2(r[0], r[1]);
    p.y = pack2(r[2], r[3]);
    p.z = pack2(r[4], r[5]);
    p.w = pack2(r[6], r[7]);
    *reinterpret_cast<uint4*>(&out[(size_t)n * D + ci]) = p;
  } else {
    float* out = (float*)outp;
    *reinterpret_cast<float4*>(&out[(size_t)n * D + ci]) =
        make_float4(r[0], r[1], r[2], r[3]);
    *reinterpret_cast<float4*>(&out[(size_t)n * D + ci + 4]) =
        make_float4(r[4], r[5], r[6], r[7]);
  }
}

}  // namespace

extern "C" void kernel_launch(void* const* d_in, const int* in_sizes, int n_in,
                              void* d_out, int out_size, void* d_ws, size_t ws_size,
                              hipStream_t stream) {
  const float* h0  = (const float*)d_in[0];
  const int*   src = (const int*)d_in[1];
  const int*   dst = (const int*)d_in[2];
  const float* W0 = (const float*)d_in[3];
  const float* b0 = (const float*)d_in[4];
  const float* W1 = (const float*)d_in[5];
  const float* b1 = (const float*)d_in[6];
  const float* W2 = (const float*)d_in[7];
  const float* b2 = (const float*)d_in[8];
  const float* W3 = (const float*)d_in[9];
  const float* b3 = (const float*)d_in[10];
  float* out = (float*)d_out;

  // workspace layout (256B aligned)
  char* w = (char*)d_ws;
  size_t off = 0;
  auto take = [&](size_t bytes) {
    char* p = w + off;
    off = (off + bytes + 255) & ~size_t(255);
    return p;
  };
  int*   deg_out = (int*)take(NN * 4);   // adjacent: one memset covers both
  int*   deg_in  = (int*)take(NN * 4);
  float* nsrc    = (float*)take(NN * 4);
  float* ndst    = (float*)take(NN * 4);
  int*   rowptr  = (int*)take((NN + 1) * 4);
  int*   le      = (int*)take(NE * 4);
  int*   col     = (int*)take(NE * 4);
  int*   bsum    = (int*)take(NBLK * 4);
  bhalf* xbuf    = (bhalf*)take((size_t)NN * 128 * 2);  // bf16 GEMM outputs
  bhalf* hbuf    = (bhalf*)take((size_t)NN * 128 * 2);  // bf16 gather outputs
  bhalf* wt0     = (bhalf*)take(128 * 128 * 2);         // W0^T bf16
  bhalf* wt1     = (bhalf*)take(128 * 128 * 2);         // W1^T bf16
  bhalf* wt2     = (bhalf*)take(128 * 128 * 2);         // W2^T bf16
  bhalf* wt3     = (bhalf*)take(64 * 128 * 2);          // W3^T bf16
  (void)ws_size; (void)in_sizes; (void)n_in; (void)out_size;

  // zero both degree arrays (contiguous)
  hipMemsetAsync(deg_out, 0, (size_t)((char*)nsrc - (char*)deg_out), stream);

  // 1) degree atomics (full issue rate) + W->Wt bf16 convert (tiny co-tenant)
  deg_wcvt_kernel<<<EB + WCVT_BLOCKS, 256, 0, stream>>>(
      src, dst, deg_out, deg_in, le, W0, W1, W2, W3, wt0, wt1, wt2, wt3);
  // 2) scan phase1 + norms + layer-0 MFMA GEMM (fills the idle machine)
  scan1_gemm0_kernel<<<NBLK + MFMA_BLOCKS, 256, 0, stream>>>(
      deg_out, deg_in, bsum, nsrc, ndst, h0, wt0, xbuf);
  // 3) scan phases 2+3
  scan23<<<NBLK, SCAN_BLK, 0, stream>>>(deg_in, bsum, rowptr);
  // 4) CSR fill
  scatter_kernel<<<EB, 256, 0, stream>>>(src, dst, le, rowptr, col);

  const int G4_128 = (NN / 4 * 64) / 256;        // 3125
  const int G4_64  = (NN / 8 * 64 + 255) / 256;  // 1563

  // layer 0: x0 unscaled bf16 -> gather applies ns[col]; h1 bf16
  gather4_kernel<128, true, true, true><<<G4_128, 256, 0, stream>>>(
      xbuf, rowptr, col, ndst, b0, nsrc, hbuf);
  // layer 1 (MFMA)
  gemm_mfma<128, true, bhalf><<<MFMA_BLOCKS, 256, 0, stream>>>(hbuf, wt1, nsrc, xbuf);
  gather4_kernel<128, true, false, true><<<G4_128, 256, 0, stream>>>(
      xbuf, rowptr, col, ndst, b1, nullptr, hbuf);
  // layer 2 (MFMA)
  gemm_mfma<128, true, bhalf><<<MFMA_BLOCKS, 256, 0, stream>>>(hbuf, wt2, nsrc, xbuf);
  gather4_kernel<128, true, false, true><<<G4_128, 256, 0, stream>>>(
      xbuf, rowptr, col, ndst, b2, nullptr, hbuf);
  // layer 3 (MFMA, DO=64): no relu, fp32 straight to d_out
  gemm_mfma<64, true, bhalf><<<MFMA_BLOCKS, 256, 0, stream>>>(hbuf, wt3, nsrc, xbuf);
  gather4_kernel<64, false, false, false><<<G4_64, 256, 0, stream>>>(
      xbuf, rowptr, col, ndst, b3, nullptr, out);
}